// Round 7
// baseline (1521.077 us; speedup 1.0000x reference)
//
#include <hip/hip_runtime.h>

#define NN 20000
#define NE 640000
#define CC 128
#define HH 8
#define GG 50
#define FF 128
#define LL 3
#define TE 128   // edges per tile in k_edge

typedef unsigned short u16;
typedef __attribute__((ext_vector_type(8))) short bf16x8;   // 8 bf16 = 4 VGPRs
typedef __attribute__((ext_vector_type(4))) float f32x4;

__device__ __forceinline__ u16 f2bf(float f) {
    union { float f; unsigned int i; } x; x.f = f;
    unsigned int r = x.i + 0x7fffu + ((x.i >> 16) & 1u);
    return (u16)(r >> 16);
}
// ShiftedSoftplus: softplus(x)-log2 via HW exp/log; |err| ~1e-7, far below bf16 noise
__device__ __forceinline__ float sspf(float x) {
    return fmaxf(x, 0.0f) + __logf(1.0f + __expf(-fabsf(x))) - 0.69314718055994531f;
}

// ---------------- CSR build (sort edges by dst) ----------------
__global__ void k_zero(int* __restrict__ c, int n) {
    int i = blockIdx.x * 256 + threadIdx.x;
    if (i < n) c[i] = 0;
}

__global__ void k_zerof(float* __restrict__ c, int n) {
    int i = blockIdx.x * 256 + threadIdx.x;
    if (i < n) c[i] = 0.0f;
}

__global__ void k_hist(const int* __restrict__ ei, int* __restrict__ c) {
    int e = blockIdx.x * 256 + threadIdx.x;
    if (e < NE) atomicAdd(&c[ei[NE + e]], 1);
}

__global__ __launch_bounds__(1024) void k_scan(const int* __restrict__ cnt,
                                               int* __restrict__ rowptr,
                                               int* __restrict__ cursor) {
    __shared__ int sums[1024];
    const int t = threadIdx.x;
    int local[20];
    int base = t * 20;
    int s = 0;
    #pragma unroll
    for (int i = 0; i < 20; ++i) {
        int idx = base + i;
        int v = (idx < NN) ? cnt[idx] : 0;
        local[i] = s; s += v;
    }
    sums[t] = s;
    __syncthreads();
    for (int off = 1; off < 1024; off <<= 1) {
        int v = (t >= off) ? sums[t - off] : 0;
        __syncthreads();
        sums[t] += v;
        __syncthreads();
    }
    int excl = (t == 0) ? 0 : sums[t - 1];
    #pragma unroll
    for (int i = 0; i < 20; ++i) {
        int idx = base + i;
        if (idx < NN) { int r = excl + local[i]; rowptr[idx] = r; cursor[idx] = r; }
    }
    if (t == 1023) rowptr[NN] = sums[1023];
}

__global__ void k_scatter(const int* __restrict__ ei, int* __restrict__ cursor,
                          int* __restrict__ srcp, int* __restrict__ dstp) {
    int e = blockIdx.x * 256 + threadIdx.x;
    if (e >= NE) return;
    int s = ei[e], d = ei[NE + e];
    int pp = atomicAdd(&cursor[d], 1);
    srcp[pp] = s; dstp[pp] = d;
}

__global__ void k_hinit(const int* __restrict__ z, const float* __restrict__ emb,
                        float* __restrict__ h) {
    int i = blockIdx.x * 256 + threadIdx.x;
    if (i < NN * CC) h[i] = emb[z[i >> 7] * CC + (i & 127)];
}

// ---------------- weight prep (once per call) ----------------
// w1tg[l][c][k64] (k>=50 zero), bf16 transposed
__global__ void k_prep1(const float* __restrict__ w1, u16* __restrict__ w1tg) {
    int i = blockIdx.x * 256 + threadIdx.x;
    if (i < LL * 128 * 64) {
        int l = i / (128 * 64); int r = i % (128 * 64); int c = r >> 6, k = r & 63;
        float v = (k < GG) ? w1[(l * GG + k) * FF + c] : 0.0f;
        w1tg[i] = f2bf(v);
    }
}

// W23[l][k][cp] = sum_c w2[l][k][c] * we[l][c][cp]; stored transposed bf16 [l][cp][k]
__global__ __launch_bounds__(128) void k_prep23(const float* __restrict__ w2,
                                                const float* __restrict__ we,
                                                u16* __restrict__ w23tg) {
    int l = blockIdx.x >> 7, k = blockIdx.x & 127;
    int cp = threadIdx.x;
    float s = 0.0f;
    for (int c = 0; c < FF; ++c)
        s = fmaf(w2[((size_t)l * FF + k) * FF + c], we[((size_t)l * FF + c) * CC + cp], s);
    w23tg[((size_t)l * CC + cp) * FF + k] = f2bf(s);
}

// b23[l][cp] = be[l][cp] + sum_k b2[l][k] * we[l][k][cp]
__global__ __launch_bounds__(128) void k_prepb(const float* __restrict__ b2,
                                               const float* __restrict__ we,
                                               const float* __restrict__ be,
                                               float* __restrict__ b23g) {
    int l = blockIdx.x;
    int cp = threadIdx.x;
    float s = be[l * CC + cp];
    for (int k = 0; k < FF; ++k)
        s = fmaf(b2[l * FF + k], we[((size_t)l * FF + k) * CC + cp], s);
    b23g[l * CC + cp] = s;
}

// node weights: wn[((l*5+m)*128 + c)*128 + k] = bf16(W_m[l][k][c]); m: q,k,v,skip,l
__global__ void k_prepn(const float* __restrict__ wq, const float* __restrict__ wk,
                        const float* __restrict__ wv, const float* __restrict__ wsk,
                        const float* __restrict__ wl, u16* __restrict__ wn) {
    int i = blockIdx.x * 256 + threadIdx.x;
    if (i >= LL * 5 * 128 * 128) return;
    int k = i & 127, c = (i >> 7) & 127;
    int lm = i >> 14; int m = lm % 5, l = lm / 5;
    const float* W = (m == 0) ? wq : (m == 1) ? wk : (m == 2) ? wv : (m == 3) ? wsk : wl;
    wn[i] = f2bf(W[((size_t)l * 128 + k) * 128 + c]);
}

// ---------------- MFMA node GEMM: q/k/v/skip (grid = tiles*4, one matrix each) --
__global__ __launch_bounds__(256) void k_qkvs_mfma(
    const float* __restrict__ A, const u16* __restrict__ wnl,
    const float* __restrict__ b0, const float* __restrict__ b1p,
    const float* __restrict__ b2p, const float* __restrict__ b3p,
    float* __restrict__ o0, float* __restrict__ o1,
    float* __restrict__ o2, float* __restrict__ o3, int nrows)
{
    __shared__ __align__(16) short hb[128 * 136];
    __shared__ __align__(16) short wT[128 * 136];
    const int t = threadIdx.x, lane = t & 63, w = t >> 6;
    const int tx = lane & 15, tg = lane >> 4;
    const int m = blockIdx.x & 3, tile = blockIdx.x >> 2;
    const int n0 = tile * 128;
    // stage h tile as bf16 rows [r][k]
    for (int idx = t; idx < 128 * 32; idx += 256) {
        int r = idx >> 5, kq = idx & 31;
        int n = n0 + r;
        float4 hv;
        if (n < nrows) hv = *(const float4*)&A[(size_t)n * 128 + kq * 4];
        else { hv.x = hv.y = hv.z = hv.w = 0.0f; }
        uint2 pk = make_uint2((unsigned)f2bf(hv.x) | ((unsigned)f2bf(hv.y) << 16),
                              (unsigned)f2bf(hv.z) | ((unsigned)f2bf(hv.w) << 16));
        *(uint2*)&hb[r * 136 + kq * 4] = pk;
    }
    const u16* Wm = wnl + (size_t)m * 16384;
    for (int idx = t; idx < 128 * 16; idx += 256) {
        int c = idx >> 4, oc = idx & 15;
        *(float4*)&wT[c * 136 + oc * 8] = *(const float4*)&Wm[c * 128 + oc * 8];
    }
    __syncthreads();
    const f32x4 zf4 = { 0.0f, 0.0f, 0.0f, 0.0f };
    f32x4 acc[2][8];
    #pragma unroll
    for (int mt = 0; mt < 2; ++mt)
        #pragma unroll
        for (int nt = 0; nt < 8; ++nt) acc[mt][nt] = zf4;
    #pragma unroll
    for (int s = 0; s < 4; ++s) {
        bf16x8 af[2], bfr[8];
        #pragma unroll
        for (int mt = 0; mt < 2; ++mt)
            af[mt] = *(const bf16x8*)&wT[(w * 32 + mt * 16 + tx) * 136 + s * 32 + tg * 8];
        #pragma unroll
        for (int nt = 0; nt < 8; ++nt)
            bfr[nt] = *(const bf16x8*)&hb[(nt * 16 + tx) * 136 + s * 32 + tg * 8];
        #pragma unroll
        for (int mt = 0; mt < 2; ++mt)
            #pragma unroll
            for (int nt = 0; nt < 8; ++nt)
                acc[mt][nt] = __builtin_amdgcn_mfma_f32_16x16x32_bf16(af[mt], bfr[nt], acc[mt][nt], 0, 0, 0);
    }
    const float* Bm = (m == 0) ? b0 : (m == 1) ? b1p : (m == 2) ? b2p : b3p;
    float* Om = (m == 0) ? o0 : (m == 1) ? o1 : (m == 2) ? o2 : o3;
    #pragma unroll
    for (int mt = 0; mt < 2; ++mt) {
        int c0 = w * 32 + mt * 16 + tg * 4;
        float4 bb = *(const float4*)&Bm[c0];
        #pragma unroll
        for (int nt = 0; nt < 8; ++nt) {
            int n = n0 + nt * 16 + tx;
            if (n < nrows) {
                float4 ov;
                ov.x = acc[mt][nt][0] + bb.x; ov.y = acc[mt][nt][1] + bb.y;
                ov.z = acc[mt][nt][2] + bb.z; ov.w = acc[mt][nt][3] + bb.w;
                *(float4*)&Om[(size_t)n * 128 + c0] = ov;
            }
        }
    }
}

// ---------------- MFMA update: t=ssp(num/den+skip) -> GEMM(wl) -> h += ----------
__global__ __launch_bounds__(256) void k_upd_mfma(
    const float* __restrict__ num, const float* __restrict__ den,
    const float* __restrict__ skip, const u16* __restrict__ wlT,
    const float* __restrict__ Bias, float* __restrict__ h, int nrows)
{
    __shared__ __align__(16) short tb[128 * 136];
    __shared__ __align__(16) short wT[128 * 136];
    const int t = threadIdx.x, lane = t & 63, w = t >> 6;
    const int tx = lane & 15, tg = lane >> 4;
    const int n0 = blockIdx.x * 128;
    for (int idx = t; idx < 128 * 32; idx += 256) {
        int r = idx >> 5, kq = idx & 31;
        int n = n0 + r;
        float v0 = 0, v1 = 0, v2 = 0, v3 = 0;
        if (n < nrows) {
            float4 nv = *(const float4*)&num[(size_t)n * 128 + kq * 4];
            float4 sv = *(const float4*)&skip[(size_t)n * 128 + kq * 4];
            float dd = den[n * HH + (kq >> 2)] + 1e-16f;
            v0 = sspf(nv.x / dd + sv.x); v1 = sspf(nv.y / dd + sv.y);
            v2 = sspf(nv.z / dd + sv.z); v3 = sspf(nv.w / dd + sv.w);
        }
        uint2 pk = make_uint2((unsigned)f2bf(v0) | ((unsigned)f2bf(v1) << 16),
                              (unsigned)f2bf(v2) | ((unsigned)f2bf(v3) << 16));
        *(uint2*)&tb[r * 136 + kq * 4] = pk;
    }
    for (int idx = t; idx < 128 * 16; idx += 256) {
        int c = idx >> 4, oc = idx & 15;
        *(float4*)&wT[c * 136 + oc * 8] = *(const float4*)&wlT[c * 128 + oc * 8];
    }
    __syncthreads();
    const f32x4 zf4 = { 0.0f, 0.0f, 0.0f, 0.0f };
    f32x4 acc[2][8];
    #pragma unroll
    for (int mt = 0; mt < 2; ++mt)
        #pragma unroll
        for (int nt = 0; nt < 8; ++nt) acc[mt][nt] = zf4;
    #pragma unroll
    for (int s = 0; s < 4; ++s) {
        bf16x8 af[2], bfr[8];
        #pragma unroll
        for (int mt = 0; mt < 2; ++mt)
            af[mt] = *(const bf16x8*)&wT[(w * 32 + mt * 16 + tx) * 136 + s * 32 + tg * 8];
        #pragma unroll
        for (int nt = 0; nt < 8; ++nt)
            bfr[nt] = *(const bf16x8*)&tb[(nt * 16 + tx) * 136 + s * 32 + tg * 8];
        #pragma unroll
        for (int mt = 0; mt < 2; ++mt)
            #pragma unroll
            for (int nt = 0; nt < 8; ++nt)
                acc[mt][nt] = __builtin_amdgcn_mfma_f32_16x16x32_bf16(af[mt], bfr[nt], acc[mt][nt], 0, 0, 0);
    }
    #pragma unroll
    for (int mt = 0; mt < 2; ++mt) {
        int c0 = w * 32 + mt * 16 + tg * 4;
        float4 bb = *(const float4*)&Bias[c0];
        #pragma unroll
        for (int nt = 0; nt < 8; ++nt) {
            int n = n0 + nt * 16 + tx;
            if (n < nrows) {
                float4 hv = *(const float4*)&h[(size_t)n * 128 + c0];
                hv.x += acc[mt][nt][0] + bb.x; hv.y += acc[mt][nt][1] + bb.y;
                hv.z += acc[mt][nt][2] + bb.z; hv.w += acc[mt][nt][3] + bb.w;
                *(float4*)&h[(size_t)n * 128 + c0] = hv;
            }
        }
    }
}

// ---------------- persistent MFMA edge pipeline (4 barriers, walk || staging) ----
// 16 waves (1024 thr). Wave w: wr=w>>2 owns c-rows [wr*32,+32), wc=w&3 owns
// edge-cols [wc*32,+32). C^T[c][r] = W^T[c][k] * X^T[k][r], MFMA 16x16x32_bf16.
// attr(T+1) is staged (threads 544-799) concurrently with the walk (threads <544).
__global__ __launch_bounds__(1024, 4) void k_edge(
    const int* __restrict__ srcp, const int* __restrict__ dstp,
    const float* __restrict__ pos,
    const u16* __restrict__ w1tg, const u16* __restrict__ w23tg,
    const float* __restrict__ b1, const float* __restrict__ b23,
    const float* __restrict__ qn, const float* __restrict__ kn, const float* __restrict__ vn,
    float* __restrict__ num, float* __restrict__ den, int ntiles)
{
    __shared__ __align__(16) short w1T[128 * 72];    // [c][k64]
    __shared__ __align__(16) short wcT[128 * 136];   // W23^T [c][k128]
    __shared__ __align__(16) short attrB[128 * 72];  // attr [r][k64] (double-duty via pipeline)
    __shared__ __align__(16) short a2[128 * 136];    // act1 bf16 / walk-lo f32 [r][68]
    __shared__ __align__(16) short wkB[128 * 136];   // walk-hi f32 [r][68]
    __shared__ int sls2[2][128], dls2[2][128];

    const int t = threadIdx.x;
    const int lane = t & 63;
    const int w = t >> 6;
    const int wr = w >> 2, wc = w & 3;
    const int tx = lane & 15, tg = lane >> 4;

    for (int idx = t; idx < 128 * 8; idx += 1024) {
        int c = idx >> 3, pp = idx & 7;
        *(float4*)&w1T[c * 72 + pp * 8] = *(const float4*)&w1tg[c * 64 + pp * 8];
    }
    for (int idx = t; idx < 128 * 16; idx += 1024) {
        int c = idx >> 4, pp = idx & 15;
        *(float4*)&wcT[c * 136 + pp * 8] = *(const float4*)&w23tg[c * 128 + pp * 8];
    }
    float b1v[8], bcv[8];
    #pragma unroll
    for (int mt = 0; mt < 2; ++mt)
        #pragma unroll
        for (int q = 0; q < 4; ++q) {
            int c = wr * 32 + mt * 16 + tg * 4 + q;
            b1v[mt * 4 + q] = b1[c]; bcv[mt * 4 + q] = b23[c];
        }

    float* a2f = (float*)a2;
    float* wkf = (float*)wkB;

    const float STEP = 10.0f / 49.0f;
    const float COEF = -0.5f / (STEP * STEP);
    const f32x4 zf4 = { 0.0f, 0.0f, 0.0f, 0.0f };

    // stage tile (idx + gaussian attr) -- executed by 256 threads (ts in [0,256))
    auto stage = [&](int tile, int nx, int ts) {
        int r = ts >> 1, half = ts & 1;
        int e = tile * TE + r;
        int sn = srcp[e], dn = dstp[e];
        if (half == 0) { sls2[nx][r] = sn; dls2[nx][r] = dn; }
        float dx = pos[dn * 3 + 0] - pos[sn * 3 + 0];
        float dy = pos[dn * 3 + 1] - pos[sn * 3 + 1];
        float dz = pos[dn * 3 + 2] - pos[sn * 3 + 2];
        float dd = sqrtf(dx * dx + dy * dy + dz * dz + 1e-12f);
        #pragma unroll
        for (int oct = 0; oct < 4; ++oct) {
            int k0 = half * 32 + oct * 8;
            __align__(16) u16 tmp[8];
            #pragma unroll
            for (int j = 0; j < 8; ++j) {
                int k = k0 + j;
                float v = 0.0f;
                if (k < GG) { float df = dd - STEP * (float)k; v = __expf(COEF * df * df); }
                tmp[j] = f2bf(v);
            }
            *(float4*)&attrB[r * 72 + k0] = *(float4*)&tmp[0];
        }
    };

    // prologue: stage first tile
    if (blockIdx.x < (unsigned)ntiles && t >= 544 && t < 800) stage(blockIdx.x, 0, t - 544);
    __syncthreads();

    int it = 0;
    for (int tile = blockIdx.x; tile < ntiles; tile += gridDim.x, ++it) {
        const int cur = it & 1, nx = cur ^ 1;

        // ---- GEMM1^T from attrB -> act1 regs ----
        f32x4 acc[2][2];
        #pragma unroll
        for (int mt = 0; mt < 2; ++mt)
            #pragma unroll
            for (int nt = 0; nt < 2; ++nt) acc[mt][nt] = zf4;
        #pragma unroll
        for (int s = 0; s < 2; ++s) {
            bf16x8 af[2], bfr[2];
            #pragma unroll
            for (int mt = 0; mt < 2; ++mt)
                af[mt] = *(const bf16x8*)&w1T[(wr * 32 + mt * 16 + tx) * 72 + s * 32 + tg * 8];
            #pragma unroll
            for (int nt = 0; nt < 2; ++nt)
                bfr[nt] = *(const bf16x8*)&attrB[(wc * 32 + nt * 16 + tx) * 72 + s * 32 + tg * 8];
            #pragma unroll
            for (int mt = 0; mt < 2; ++mt)
                #pragma unroll
                for (int nt = 0; nt < 2; ++nt)
                    acc[mt][nt] = __builtin_amdgcn_mfma_f32_16x16x32_bf16(af[mt], bfr[nt], acc[mt][nt], 0, 0, 0);
        }
        // ssp(. + b1) -> a2[r][c]
        #pragma unroll
        for (int mt = 0; mt < 2; ++mt) {
            int c0 = wr * 32 + mt * 16 + tg * 4;
            #pragma unroll
            for (int nt = 0; nt < 2; ++nt) {
                int r = wc * 32 + nt * 16 + tx;
                u16 o0 = f2bf(sspf(acc[mt][nt][0] + b1v[mt * 4 + 0]));
                u16 o1 = f2bf(sspf(acc[mt][nt][1] + b1v[mt * 4 + 1]));
                u16 o2 = f2bf(sspf(acc[mt][nt][2] + b1v[mt * 4 + 2]));
                u16 o3 = f2bf(sspf(acc[mt][nt][3] + b1v[mt * 4 + 3]));
                uint2 pkd = make_uint2((unsigned)o0 | ((unsigned)o1 << 16),
                                       (unsigned)o2 | ((unsigned)o3 << 16));
                *(uint2*)&a2[r * 136 + c0] = pkd;
            }
        }
        __syncthreads();   // B_a: act1 ready; attrB dead

        // ---- issue epilogue gathers (fly under GEMM23's MFMAs) ----
        int rr2[2], sn2[2], dn2[2];
        #pragma unroll
        for (int nt = 0; nt < 2; ++nt) {
            rr2[nt] = wc * 32 + nt * 16 + tx;
            sn2[nt] = sls2[cur][rr2[nt]];
            dn2[nt] = dls2[cur][rr2[nt]];
        }
        float4 pq[2][2], pk[2][2], pv[2][2];
        #pragma unroll
        for (int mt = 0; mt < 2; ++mt) {
            int c0 = wr * 32 + mt * 16 + tg * 4;
            #pragma unroll
            for (int nt = 0; nt < 2; ++nt) {
                pq[mt][nt] = *(const float4*)&qn[(size_t)dn2[nt] * CC + c0];
                pk[mt][nt] = *(const float4*)&kn[(size_t)sn2[nt] * CC + c0];
                pv[mt][nt] = *(const float4*)&vn[(size_t)sn2[nt] * CC + c0];
            }
        }

        // ---- GEMM23^T: ep^T = W23^T * act1^T (K=128) ----
        #pragma unroll
        for (int mt = 0; mt < 2; ++mt)
            #pragma unroll
            for (int nt = 0; nt < 2; ++nt) acc[mt][nt] = zf4;
        #pragma unroll
        for (int s = 0; s < 4; ++s) {
            bf16x8 af[2], bfr[2];
            #pragma unroll
            for (int mt = 0; mt < 2; ++mt)
                af[mt] = *(const bf16x8*)&wcT[(wr * 32 + mt * 16 + tx) * 136 + s * 32 + tg * 8];
            #pragma unroll
            for (int nt = 0; nt < 2; ++nt)
                bfr[nt] = *(const bf16x8*)&a2[(wc * 32 + nt * 16 + tx) * 136 + s * 32 + tg * 8];
            #pragma unroll
            for (int mt = 0; mt < 2; ++mt)
                #pragma unroll
                for (int nt = 0; nt < 2; ++nt)
                    acc[mt][nt] = __builtin_amdgcn_mfma_f32_16x16x32_bf16(af[mt], bfr[nt], acc[mt][nt], 0, 0, 0);
        }
        __syncthreads();   // B_b: all reads of a2 done

        // ---- epilogue: logits, w=exp, write w*ve f32 -> a2f(lo) / wkf(hi) ----
        #pragma unroll
        for (int mt = 0; mt < 2; ++mt) {
            int c0 = wr * 32 + mt * 16 + tg * 4;
            int h = wr * 2 + mt;
            #pragma unroll
            for (int nt = 0; nt < 2; ++nt) {
                float ep0 = acc[mt][nt][0] + bcv[mt * 4 + 0];
                float ep1 = acc[mt][nt][1] + bcv[mt * 4 + 1];
                float ep2 = acc[mt][nt][2] + bcv[mt * 4 + 2];
                float ep3 = acc[mt][nt][3] + bcv[mt * 4 + 3];
                float lg = pq[mt][nt].x * (pk[mt][nt].x + ep0)
                         + pq[mt][nt].y * (pk[mt][nt].y + ep1)
                         + pq[mt][nt].z * (pk[mt][nt].z + ep2)
                         + pq[mt][nt].w * (pk[mt][nt].w + ep3);
                lg += __shfl_xor(lg, 16);
                lg += __shfl_xor(lg, 32);
                float wgt = __expf(lg * 0.25f);
                float4 wv;
                wv.x = wgt * (pv[mt][nt].x + ep0); wv.y = wgt * (pv[mt][nt].y + ep1);
                wv.z = wgt * (pv[mt][nt].z + ep2); wv.w = wgt * (pv[mt][nt].w + ep3);
                if (c0 < 64) *(float4*)&a2f[rr2[nt] * 68 + c0] = wv;
                else         *(float4*)&wkf[rr2[nt] * 68 + (c0 - 64)] = wv;
                if (tg == 0) {
                    if (h < 4) a2f[rr2[nt] * 68 + 64 + h] = wgt;
                    else       wkf[rr2[nt] * 68 + 64 + (h - 4)] = wgt;
                }
            }
        }
        __syncthreads();   // B_c: walk data ready

        // ---- walk (t<544) || stage next tile (544<=t<800) ----
        if (t < 544) {
            int ch = t % 136;
            int r0 = (t / 136) * 32;
            const int* dls = dls2[cur];
            float run = 0.0f;
            #pragma unroll 4
            for (int rr = 0; rr < 32; ++rr) {
                int r = r0 + rr;
                float v;
                if (ch < 64)       v = a2f[r * 68 + ch];
                else if (ch < 128) v = wkf[r * 68 + (ch - 64)];
                else if (ch < 132) v = a2f[r * 68 + 64 + (ch - 128)];
                else               v = wkf[r * 68 + 64 + (ch - 132)];
                run += v;
                if (rr == 31 || dls[r + 1] != dls[r]) {
                    int dn = dls[r];
                    if (ch < 128) atomicAdd(&num[(size_t)dn * CC + ch], run);
                    else          atomicAdd(&den[(size_t)dn * HH + (ch - 128)], run);
                    run = 0.0f;
                }
            }
        } else if (t < 800) {
            int nt2 = tile + gridDim.x;
            if (nt2 < ntiles) stage(nt2, nx, t - 544);
        }
        __syncthreads();   // B_d: close iteration
    }
}

// ---------------- output head ----------------
__global__ __launch_bounds__(64) void k_head(
    const float* __restrict__ h,
    const float* __restrict__ w1, const float* __restrict__ b1,
    const float* __restrict__ w2, const float* __restrict__ b2,
    float* __restrict__ out)
{
    const int n = blockIdx.x;
    const int j = threadIdx.x;
    float acc = 0.0f;
    for (int k = 0; k < CC; ++k)
        acc = fmaf(h[(size_t)n * CC + k], w1[k * 64 + j], acc);
    float m = sspf(acc + b1[j]);
    float o = m * w2[j];
    #pragma unroll
    for (int msk = 32; msk > 0; msk >>= 1) o += __shfl_xor(o, msk);
    if (j == 0) out[n] = o + b2[0];
}

extern "C" void kernel_launch(void* const* d_in, const int* in_sizes, int n_in,
                              void* d_out, int out_size, void* d_ws, size_t ws_size,
                              hipStream_t stream)
{
    const int*   z   = (const int*)d_in[0];
    const float* pos = (const float*)d_in[1];
    const int*   ei  = (const int*)d_in[2];
    const float* emb = (const float*)d_in[3];
    const float* w1  = (const float*)d_in[4];
    const float* b1  = (const float*)d_in[5];
    const float* w2  = (const float*)d_in[6];
    const float* b2  = (const float*)d_in[7];
    const float* wq  = (const float*)d_in[8];
    const float* bq  = (const float*)d_in[9];
    const float* wk  = (const float*)d_in[10];
    const float* bk  = (const float*)d_in[11];
    const float* wv  = (const float*)d_in[12];
    const float* bv  = (const float*)d_in[13];
    const float* we  = (const float*)d_in[14];
    const float* be  = (const float*)d_in[15];
    const float* wsk = (const float*)d_in[16];
    const float* bsk = (const float*)d_in[17];
    const float* wl  = (const float*)d_in[18];
    const float* bl  = (const float*)d_in[19];
    const float* wo1 = (const float*)d_in[20];
    const float* bo1 = (const float*)d_in[21];
    const float* wo2 = (const float*)d_in[22];
    const float* bo2 = (const float*)d_in[23];

    char* p = (char*)d_ws;
    auto alloc = [&](size_t bytes) -> void* {
        void* r = (void*)p; p += (bytes + 255) & ~(size_t)255; return r;
    };
    float* h    = (float*)alloc((size_t)NN * CC * 4);
    float* q    = (float*)alloc((size_t)NN * CC * 4);
    float* kk   = (float*)alloc((size_t)NN * CC * 4);
    float* vv   = (float*)alloc((size_t)NN * CC * 4);
    float* skip = (float*)alloc((size_t)NN * CC * 4);
    float* num  = (float*)alloc((size_t)NN * CC * 4);
    float* den  = (float*)alloc((size_t)NN * HH * 4);   // contiguous after num
    u16* w1tg  = (u16*)alloc((size_t)LL * 128 * 64 * 2);
    u16* w23tg = (u16*)alloc((size_t)LL * 128 * 128 * 2);
    float* b23g = (float*)alloc((size_t)LL * 128 * 4);
    u16* wn    = (u16*)alloc((size_t)LL * 5 * 128 * 128 * 2);
    int* count  = (int*)alloc((size_t)(NN + 1) * 4);
    int* rowptr = (int*)alloc((size_t)(NN + 1) * 4);
    int* cursor = (int*)alloc((size_t)NN * 4);
    int* srcp   = (int*)alloc((size_t)NE * 4);
    int* dstp   = (int*)alloc((size_t)NE * 4);

    k_zero<<<(NN + 255) / 256, 256, 0, stream>>>(count, NN);
    k_hist<<<(NE + 255) / 256, 256, 0, stream>>>(ei, count);
    k_scan<<<1, 1024, 0, stream>>>(count, rowptr, cursor);
    k_scatter<<<(NE + 255) / 256, 256, 0, stream>>>(ei, cursor, srcp, dstp);
    k_hinit<<<(NN * CC + 255) / 256, 256, 0, stream>>>(z, emb, h);
    k_prep1<<<(LL * 128 * 64 + 255) / 256, 256, 0, stream>>>(w1, w1tg);
    k_prep23<<<LL * 128, 128, 0, stream>>>(w2, we, w23tg);
    k_prepb<<<LL, 128, 0, stream>>>(b2, we, be, b23g);
    k_prepn<<<(LL * 5 * 128 * 128 + 255) / 256, 256, 0, stream>>>(wq, wk, wv, wsk, wl, wn);

    const int NT = (NN + 127) / 128;   // 157
    const int nzf = NN * CC + NN * HH;
    for (int l = 0; l < LL; ++l) {
        const u16* wnl = wn + (size_t)l * 5 * 16384;
        k_qkvs_mfma<<<NT * 4, 256, 0, stream>>>(h, wnl,
            bq + l * CC, bk + l * CC, bv + l * CC, bsk + l * CC,
            q, kk, vv, skip, NN);
        k_zerof<<<(nzf + 255) / 256, 256, 0, stream>>>(num, nzf);
        k_edge<<<256, 1024, 0, stream>>>(srcp, dstp, pos,
            w1tg + (size_t)l * 128 * 64, w23tg + (size_t)l * 128 * 128,
            b1 + l * FF, b23g + l * CC,
            q, kk, vv, num, den, NE / TE);
        k_upd_mfma<<<NT, 256, 0, stream>>>(num, den, skip,
            wnl + 4 * 16384, bl + l * CC, h, NN);
    }
    k_head<<<NN, 64, 0, stream>>>(h, wo1, bo1, wo2, bo2, (float*)d_out);
}

// Round 8
// 1154.841 us; speedup vs baseline: 1.3171x; 1.3171x over previous
//
#include <hip/hip_runtime.h>

#define NN 20000
#define NE 640000
#define CC 128
#define HH 8
#define GG 50
#define FF 128
#define LL 3
#define TE 128   // edges per tile in k_edge

typedef unsigned short u16;
typedef __attribute__((ext_vector_type(8))) short bf16x8;   // 8 bf16 = 4 VGPRs
typedef __attribute__((ext_vector_type(4))) float f32x4;

__device__ __forceinline__ u16 f2bf(float f) {
    union { float f; unsigned int i; } x; x.f = f;
    unsigned int r = x.i + 0x7fffu + ((x.i >> 16) & 1u);
    return (u16)(r >> 16);
}
// ShiftedSoftplus: softplus(x)-log2 via HW exp/log; |err| ~1e-7, far below bf16 noise
__device__ __forceinline__ float sspf(float x) {
    return fmaxf(x, 0.0f) + __logf(1.0f + __expf(-fabsf(x))) - 0.69314718055994531f;
}

// ---------------- CSR build (sort edges by dst) ----------------
__global__ void k_zero(int* __restrict__ c, int n) {
    int i = blockIdx.x * 256 + threadIdx.x;
    if (i < n) c[i] = 0;
}

__global__ void k_hist(const int* __restrict__ ei, int* __restrict__ c) {
    int e = blockIdx.x * 256 + threadIdx.x;
    if (e < NE) atomicAdd(&c[ei[NE + e]], 1);
}

__global__ __launch_bounds__(1024) void k_scan(const int* __restrict__ cnt,
                                               int* __restrict__ rowptr,
                                               int* __restrict__ cursor) {
    __shared__ int sums[1024];
    const int t = threadIdx.x;
    int local[20];
    int base = t * 20;
    int s = 0;
    #pragma unroll
    for (int i = 0; i < 20; ++i) {
        int idx = base + i;
        int v = (idx < NN) ? cnt[idx] : 0;
        local[i] = s; s += v;
    }
    sums[t] = s;
    __syncthreads();
    for (int off = 1; off < 1024; off <<= 1) {
        int v = (t >= off) ? sums[t - off] : 0;
        __syncthreads();
        sums[t] += v;
        __syncthreads();
    }
    int excl = (t == 0) ? 0 : sums[t - 1];
    #pragma unroll
    for (int i = 0; i < 20; ++i) {
        int idx = base + i;
        if (idx < NN) { int r = excl + local[i]; rowptr[idx] = r; cursor[idx] = r; }
    }
    if (t == 1023) rowptr[NN] = sums[1023];
}

__global__ void k_scatter(const int* __restrict__ ei, int* __restrict__ cursor,
                          int* __restrict__ srcp, int* __restrict__ dstp) {
    int e = blockIdx.x * 256 + threadIdx.x;
    if (e >= NE) return;
    int s = ei[e], d = ei[NE + e];
    int pp = atomicAdd(&cursor[d], 1);
    srcp[pp] = s; dstp[pp] = d;
}

__global__ void k_hinit(const int* __restrict__ z, const float* __restrict__ emb,
                        float* __restrict__ h) {
    int i = blockIdx.x * 256 + threadIdx.x;
    if (i < NN * CC) h[i] = emb[z[i >> 7] * CC + (i & 127)];
}

// ---------------- weight prep (once per call) ----------------
__global__ void k_prep1(const float* __restrict__ w1, u16* __restrict__ w1tg) {
    int i = blockIdx.x * 256 + threadIdx.x;
    if (i < LL * 128 * 64) {
        int l = i / (128 * 64); int r = i % (128 * 64); int c = r >> 6, k = r & 63;
        float v = (k < GG) ? w1[(l * GG + k) * FF + c] : 0.0f;
        w1tg[i] = f2bf(v);
    }
}

// W23[l][k][cp] = sum_c w2[l][k][c] * we[l][c][cp]; stored transposed bf16 [l][cp][k]
__global__ __launch_bounds__(128) void k_prep23(const float* __restrict__ w2,
                                                const float* __restrict__ we,
                                                u16* __restrict__ w23tg) {
    int l = blockIdx.x >> 7, k = blockIdx.x & 127;
    int cp = threadIdx.x;
    float s = 0.0f;
    for (int c = 0; c < FF; ++c)
        s = fmaf(w2[((size_t)l * FF + k) * FF + c], we[((size_t)l * FF + c) * CC + cp], s);
    w23tg[((size_t)l * CC + cp) * FF + k] = f2bf(s);
}

// b23[l][cp] = be[l][cp] + sum_k b2[l][k] * we[l][k][cp]
__global__ __launch_bounds__(128) void k_prepb(const float* __restrict__ b2,
                                               const float* __restrict__ we,
                                               const float* __restrict__ be,
                                               float* __restrict__ b23g) {
    int l = blockIdx.x;
    int cp = threadIdx.x;
    float s = be[l * CC + cp];
    for (int k = 0; k < FF; ++k)
        s = fmaf(b2[l * FF + k], we[((size_t)l * FF + k) * CC + cp], s);
    b23g[l * CC + cp] = s;
}

// node weights: wn[((l*5+m)*128 + c)*128 + k] = bf16(W_m[l][k][c]); m: q,k,v,skip,l
__global__ void k_prepn(const float* __restrict__ wq, const float* __restrict__ wk,
                        const float* __restrict__ wv, const float* __restrict__ wsk,
                        const float* __restrict__ wl, u16* __restrict__ wn) {
    int i = blockIdx.x * 256 + threadIdx.x;
    if (i >= LL * 5 * 128 * 128) return;
    int k = i & 127, c = (i >> 7) & 127;
    int lm = i >> 14; int m = lm % 5, l = lm / 5;
    const float* W = (m == 0) ? wq : (m == 1) ? wk : (m == 2) ? wv : (m == 3) ? wsk : wl;
    wn[i] = f2bf(W[((size_t)l * 128 + k) * 128 + c]);
}

// ---------------- MFMA node GEMM: q/k/v/skip (grid = tiles*4, one matrix each) --
// m==0 blocks additionally zero num/den for their row range (replaces k_zerof).
__global__ __launch_bounds__(256) void k_qkvs_mfma(
    const float* __restrict__ A, const u16* __restrict__ wnl,
    const float* __restrict__ b0, const float* __restrict__ b1p,
    const float* __restrict__ b2p, const float* __restrict__ b3p,
    float* __restrict__ o0, float* __restrict__ o1,
    float* __restrict__ o2, float* __restrict__ o3,
    float* __restrict__ num, float* __restrict__ den, int nrows)
{
    __shared__ __align__(16) short hb[128 * 136];
    __shared__ __align__(16) short wT[128 * 136];
    const int t = threadIdx.x, lane = t & 63, w = t >> 6;
    const int tx = lane & 15, tg = lane >> 4;
    const int m = blockIdx.x & 3, tile = blockIdx.x >> 2;
    const int n0 = tile * 128;
    // stage h tile as bf16 rows [r][k]
    for (int idx = t; idx < 128 * 32; idx += 256) {
        int r = idx >> 5, kq = idx & 31;
        int n = n0 + r;
        float4 hv;
        if (n < nrows) hv = *(const float4*)&A[(size_t)n * 128 + kq * 4];
        else { hv.x = hv.y = hv.z = hv.w = 0.0f; }
        uint2 pk = make_uint2((unsigned)f2bf(hv.x) | ((unsigned)f2bf(hv.y) << 16),
                              (unsigned)f2bf(hv.z) | ((unsigned)f2bf(hv.w) << 16));
        *(uint2*)&hb[r * 136 + kq * 4] = pk;
    }
    const u16* Wm = wnl + (size_t)m * 16384;
    for (int idx = t; idx < 128 * 16; idx += 256) {
        int c = idx >> 4, oc = idx & 15;
        *(float4*)&wT[c * 136 + oc * 8] = *(const float4*)&Wm[c * 128 + oc * 8];
    }
    // fused zeroing of num/den for this row range (m==0 only)
    if (m == 0) {
        const float4 z4 = { 0.0f, 0.0f, 0.0f, 0.0f };
        for (int idx = t; idx < 128 * 32; idx += 256) {
            int r = idx >> 5, cq = idx & 31;
            int n = n0 + r;
            if (n < nrows) *(float4*)&num[(size_t)n * 128 + cq * 4] = z4;
        }
        for (int idx = t; idx < 256; idx += 256) {
            int r = idx >> 1, hq = idx & 1;
            int n = n0 + r * 2 + hq;   // covers 128 rows? no: idx<256 -> r<128
        }
        for (int idx = t; idx < 256; idx += 256) { (void)idx; }
        // den: 128 rows x 8 heads = 1024 floats = 256 float4
        if (t < 256) {
            int r = t >> 1, half = t & 1;
            int n = n0 + r;
            if (n < nrows) *(float4*)&den[(size_t)n * HH + half * 4] = z4;
        }
    }
    __syncthreads();
    const f32x4 zf4 = { 0.0f, 0.0f, 0.0f, 0.0f };
    f32x4 acc[2][8];
    #pragma unroll
    for (int mt = 0; mt < 2; ++mt)
        #pragma unroll
        for (int nt = 0; nt < 8; ++nt) acc[mt][nt] = zf4;
    #pragma unroll
    for (int s = 0; s < 4; ++s) {
        bf16x8 af[2], bfr[8];
        #pragma unroll
        for (int mt = 0; mt < 2; ++mt)
            af[mt] = *(const bf16x8*)&wT[(w * 32 + mt * 16 + tx) * 136 + s * 32 + tg * 8];
        #pragma unroll
        for (int nt = 0; nt < 8; ++nt)
            bfr[nt] = *(const bf16x8*)&hb[(nt * 16 + tx) * 136 + s * 32 + tg * 8];
        #pragma unroll
        for (int mt = 0; mt < 2; ++mt)
            #pragma unroll
            for (int nt = 0; nt < 8; ++nt)
                acc[mt][nt] = __builtin_amdgcn_mfma_f32_16x16x32_bf16(af[mt], bfr[nt], acc[mt][nt], 0, 0, 0);
    }
    const float* Bm = (m == 0) ? b0 : (m == 1) ? b1p : (m == 2) ? b2p : b3p;
    float* Om = (m == 0) ? o0 : (m == 1) ? o1 : (m == 2) ? o2 : o3;
    #pragma unroll
    for (int mt = 0; mt < 2; ++mt) {
        int c0 = w * 32 + mt * 16 + tg * 4;
        float4 bb = *(const float4*)&Bm[c0];
        #pragma unroll
        for (int nt = 0; nt < 8; ++nt) {
            int n = n0 + nt * 16 + tx;
            if (n < nrows) {
                float4 ov;
                ov.x = acc[mt][nt][0] + bb.x; ov.y = acc[mt][nt][1] + bb.y;
                ov.z = acc[mt][nt][2] + bb.z; ov.w = acc[mt][nt][3] + bb.w;
                *(float4*)&Om[(size_t)n * 128 + c0] = ov;
            }
        }
    }
}

// ---------------- MFMA update: t=ssp(num/den+skip) -> GEMM(wl) -> h += ----------
__global__ __launch_bounds__(256) void k_upd_mfma(
    const float* __restrict__ num, const float* __restrict__ den,
    const float* __restrict__ skip, const u16* __restrict__ wlT,
    const float* __restrict__ Bias, float* __restrict__ h, int nrows)
{
    __shared__ __align__(16) short tb[128 * 136];
    __shared__ __align__(16) short wT[128 * 136];
    const int t = threadIdx.x, lane = t & 63, w = t >> 6;
    const int tx = lane & 15, tg = lane >> 4;
    const int n0 = blockIdx.x * 128;
    for (int idx = t; idx < 128 * 32; idx += 256) {
        int r = idx >> 5, kq = idx & 31;
        int n = n0 + r;
        float v0 = 0, v1 = 0, v2 = 0, v3 = 0;
        if (n < nrows) {
            float4 nv = *(const float4*)&num[(size_t)n * 128 + kq * 4];
            float4 sv = *(const float4*)&skip[(size_t)n * 128 + kq * 4];
            float dd = den[n * HH + (kq >> 2)] + 1e-16f;
            v0 = sspf(nv.x / dd + sv.x); v1 = sspf(nv.y / dd + sv.y);
            v2 = sspf(nv.z / dd + sv.z); v3 = sspf(nv.w / dd + sv.w);
        }
        uint2 pk = make_uint2((unsigned)f2bf(v0) | ((unsigned)f2bf(v1) << 16),
                              (unsigned)f2bf(v2) | ((unsigned)f2bf(v3) << 16));
        *(uint2*)&tb[r * 136 + kq * 4] = pk;
    }
    for (int idx = t; idx < 128 * 16; idx += 256) {
        int c = idx >> 4, oc = idx & 15;
        *(float4*)&wT[c * 136 + oc * 8] = *(const float4*)&wlT[c * 128 + oc * 8];
    }
    __syncthreads();
    const f32x4 zf4 = { 0.0f, 0.0f, 0.0f, 0.0f };
    f32x4 acc[2][8];
    #pragma unroll
    for (int mt = 0; mt < 2; ++mt)
        #pragma unroll
        for (int nt = 0; nt < 8; ++nt) acc[mt][nt] = zf4;
    #pragma unroll
    for (int s = 0; s < 4; ++s) {
        bf16x8 af[2], bfr[8];
        #pragma unroll
        for (int mt = 0; mt < 2; ++mt)
            af[mt] = *(const bf16x8*)&wT[(w * 32 + mt * 16 + tx) * 136 + s * 32 + tg * 8];
        #pragma unroll
        for (int nt = 0; nt < 8; ++nt)
            bfr[nt] = *(const bf16x8*)&tb[(nt * 16 + tx) * 136 + s * 32 + tg * 8];
        #pragma unroll
        for (int mt = 0; mt < 2; ++mt)
            #pragma unroll
            for (int nt = 0; nt < 8; ++nt)
                acc[mt][nt] = __builtin_amdgcn_mfma_f32_16x16x32_bf16(af[mt], bfr[nt], acc[mt][nt], 0, 0, 0);
    }
    #pragma unroll
    for (int mt = 0; mt < 2; ++mt) {
        int c0 = w * 32 + mt * 16 + tg * 4;
        float4 bb = *(const float4*)&Bias[c0];
        #pragma unroll
        for (int nt = 0; nt < 8; ++nt) {
            int n = n0 + nt * 16 + tx;
            if (n < nrows) {
                float4 hv = *(const float4*)&h[(size_t)n * 128 + c0];
                hv.x += acc[mt][nt][0] + bb.x; hv.y += acc[mt][nt][1] + bb.y;
                hv.z += acc[mt][nt][2] + bb.z; hv.w += acc[mt][nt][3] + bb.w;
                *(float4*)&h[(size_t)n * 128 + c0] = hv;
            }
        }
    }
}

// ---------------- persistent MFMA edge pipeline (walk || stage, use-site gathers)
// 16 waves (1024 thr). Wave w: wr=w>>2 owns c-rows [wr*32,+32), wc=w&3 owns
// edge-cols [wc*32,+32). C^T[c][r] = W^T[c][k] * X^T[k][r], MFMA 16x16x32_bf16.
// attr(T+1)+indices staged (threads 544-799) concurrently with walk(T) (t<544).
// q/k/v gathers stay at use-site in the epilogue: prefetching across a GEMM
// phase spills at VGPR=64 (rounds 5,7: WRITE_SIZE 21->51/69 MB).
__global__ __launch_bounds__(1024, 4) void k_edge(
    const int* __restrict__ srcp, const int* __restrict__ dstp,
    const float* __restrict__ pos,
    const u16* __restrict__ w1tg, const u16* __restrict__ w23tg,
    const float* __restrict__ b1, const float* __restrict__ b23,
    const float* __restrict__ qn, const float* __restrict__ kn, const float* __restrict__ vn,
    float* __restrict__ num, float* __restrict__ den, int ntiles)
{
    __shared__ __align__(16) short w1T[128 * 72];    // [c][k64]
    __shared__ __align__(16) short wcT[128 * 136];   // W23^T [c][k128]
    __shared__ __align__(16) short attrB[128 * 72];  // attr [r][k64] (staged ahead)
    __shared__ __align__(16) short a2[128 * 136];    // act1 bf16 / walk-lo f32 [r][68]
    __shared__ __align__(16) short wkB[128 * 136];   // walk-hi f32 [r][68]
    __shared__ int sls2[2][128], dls2[2][128];

    const int t = threadIdx.x;
    const int lane = t & 63;
    const int w = t >> 6;
    const int wr = w >> 2, wc = w & 3;
    const int tx = lane & 15, tg = lane >> 4;

    for (int idx = t; idx < 128 * 8; idx += 1024) {
        int c = idx >> 3, pp = idx & 7;
        *(float4*)&w1T[c * 72 + pp * 8] = *(const float4*)&w1tg[c * 64 + pp * 8];
    }
    for (int idx = t; idx < 128 * 16; idx += 1024) {
        int c = idx >> 4, pp = idx & 15;
        *(float4*)&wcT[c * 136 + pp * 8] = *(const float4*)&w23tg[c * 128 + pp * 8];
    }
    float b1v[8], bcv[8];
    #pragma unroll
    for (int mt = 0; mt < 2; ++mt)
        #pragma unroll
        for (int q = 0; q < 4; ++q) {
            int c = wr * 32 + mt * 16 + tg * 4 + q;
            b1v[mt * 4 + q] = b1[c]; bcv[mt * 4 + q] = b23[c];
        }

    float* a2f = (float*)a2;
    float* wkf = (float*)wkB;

    const float STEP = 10.0f / 49.0f;
    const float COEF = -0.5f / (STEP * STEP);
    const f32x4 zf4 = { 0.0f, 0.0f, 0.0f, 0.0f };

    // stage tile (idx + gaussian attr) -- executed by 256 threads (ts in [0,256))
    auto stage = [&](int tile, int nx, int ts) {
        int r = ts >> 1, half = ts & 1;
        int e = tile * TE + r;
        int sn = srcp[e], dn = dstp[e];
        if (half == 0) { sls2[nx][r] = sn; dls2[nx][r] = dn; }
        float dx = pos[dn * 3 + 0] - pos[sn * 3 + 0];
        float dy = pos[dn * 3 + 1] - pos[sn * 3 + 1];
        float dz = pos[dn * 3 + 2] - pos[sn * 3 + 2];
        float dd = sqrtf(dx * dx + dy * dy + dz * dz + 1e-12f);
        #pragma unroll
        for (int oct = 0; oct < 4; ++oct) {
            int k0 = half * 32 + oct * 8;
            __align__(16) u16 tmp[8];
            #pragma unroll
            for (int j = 0; j < 8; ++j) {
                int k = k0 + j;
                float v = 0.0f;
                if (k < GG) { float df = dd - STEP * (float)k; v = __expf(COEF * df * df); }
                tmp[j] = f2bf(v);
            }
            *(float4*)&attrB[r * 72 + k0] = *(float4*)&tmp[0];
        }
    };

    // prologue: stage first tile
    if (blockIdx.x < (unsigned)ntiles && t >= 544 && t < 800) stage(blockIdx.x, 0, t - 544);
    __syncthreads();

    int it = 0;
    for (int tile = blockIdx.x; tile < ntiles; tile += gridDim.x, ++it) {
        const int cur = it & 1, nx = cur ^ 1;

        // ---- GEMM1^T from attrB -> act1 regs ----
        f32x4 acc[2][2];
        #pragma unroll
        for (int mt = 0; mt < 2; ++mt)
            #pragma unroll
            for (int nt = 0; nt < 2; ++nt) acc[mt][nt] = zf4;
        #pragma unroll
        for (int s = 0; s < 2; ++s) {
            bf16x8 af[2], bfr[2];
            #pragma unroll
            for (int mt = 0; mt < 2; ++mt)
                af[mt] = *(const bf16x8*)&w1T[(wr * 32 + mt * 16 + tx) * 72 + s * 32 + tg * 8];
            #pragma unroll
            for (int nt = 0; nt < 2; ++nt)
                bfr[nt] = *(const bf16x8*)&attrB[(wc * 32 + nt * 16 + tx) * 72 + s * 32 + tg * 8];
            #pragma unroll
            for (int mt = 0; mt < 2; ++mt)
                #pragma unroll
                for (int nt = 0; nt < 2; ++nt)
                    acc[mt][nt] = __builtin_amdgcn_mfma_f32_16x16x32_bf16(af[mt], bfr[nt], acc[mt][nt], 0, 0, 0);
        }
        // ssp(. + b1) -> a2[r][c]
        #pragma unroll
        for (int mt = 0; mt < 2; ++mt) {
            int c0 = wr * 32 + mt * 16 + tg * 4;
            #pragma unroll
            for (int nt = 0; nt < 2; ++nt) {
                int r = wc * 32 + nt * 16 + tx;
                u16 o0 = f2bf(sspf(acc[mt][nt][0] + b1v[mt * 4 + 0]));
                u16 o1 = f2bf(sspf(acc[mt][nt][1] + b1v[mt * 4 + 1]));
                u16 o2 = f2bf(sspf(acc[mt][nt][2] + b1v[mt * 4 + 2]));
                u16 o3 = f2bf(sspf(acc[mt][nt][3] + b1v[mt * 4 + 3]));
                uint2 pkd = make_uint2((unsigned)o0 | ((unsigned)o1 << 16),
                                       (unsigned)o2 | ((unsigned)o3 << 16));
                *(uint2*)&a2[r * 136 + c0] = pkd;
            }
        }
        __syncthreads();   // B_a: act1 ready; attrB dead

        // ---- GEMM23^T: ep^T = W23^T * act1^T (K=128) ----
        #pragma unroll
        for (int mt = 0; mt < 2; ++mt)
            #pragma unroll
            for (int nt = 0; nt < 2; ++nt) acc[mt][nt] = zf4;
        #pragma unroll
        for (int s = 0; s < 4; ++s) {
            bf16x8 af[2], bfr[2];
            #pragma unroll
            for (int mt = 0; mt < 2; ++mt)
                af[mt] = *(const bf16x8*)&wcT[(wr * 32 + mt * 16 + tx) * 136 + s * 32 + tg * 8];
            #pragma unroll
            for (int nt = 0; nt < 2; ++nt)
                bfr[nt] = *(const bf16x8*)&a2[(wc * 32 + nt * 16 + tx) * 136 + s * 32 + tg * 8];
            #pragma unroll
            for (int mt = 0; mt < 2; ++mt)
                #pragma unroll
                for (int nt = 0; nt < 2; ++nt)
                    acc[mt][nt] = __builtin_amdgcn_mfma_f32_16x16x32_bf16(af[mt], bfr[nt], acc[mt][nt], 0, 0, 0);
        }
        __syncthreads();   // B_b: all reads of a2 done

        // ---- epilogue: use-site gathers, logits, w=exp, write w*ve f32 ----
        {
            int rr2[2], sn2[2], dn2[2];
            #pragma unroll
            for (int nt = 0; nt < 2; ++nt) {
                rr2[nt] = wc * 32 + nt * 16 + tx;
                sn2[nt] = sls2[cur][rr2[nt]];
                dn2[nt] = dls2[cur][rr2[nt]];
            }
            #pragma unroll
            for (int mt = 0; mt < 2; ++mt) {
                int c0 = wr * 32 + mt * 16 + tg * 4;
                int h = wr * 2 + mt;
                #pragma unroll
                for (int nt = 0; nt < 2; ++nt) {
                    float4 kv = *(const float4*)&kn[(size_t)sn2[nt] * CC + c0];
                    float4 vv = *(const float4*)&vn[(size_t)sn2[nt] * CC + c0];
                    float4 qv = *(const float4*)&qn[(size_t)dn2[nt] * CC + c0];
                    float ep0 = acc[mt][nt][0] + bcv[mt * 4 + 0];
                    float ep1 = acc[mt][nt][1] + bcv[mt * 4 + 1];
                    float ep2 = acc[mt][nt][2] + bcv[mt * 4 + 2];
                    float ep3 = acc[mt][nt][3] + bcv[mt * 4 + 3];
                    float lg = qv.x * (kv.x + ep0) + qv.y * (kv.y + ep1)
                             + qv.z * (kv.z + ep2) + qv.w * (kv.w + ep3);
                    lg += __shfl_xor(lg, 16);
                    lg += __shfl_xor(lg, 32);
                    float wgt = __expf(lg * 0.25f);
                    float4 wv;
                    wv.x = wgt * (vv.x + ep0); wv.y = wgt * (vv.y + ep1);
                    wv.z = wgt * (vv.z + ep2); wv.w = wgt * (vv.w + ep3);
                    if (c0 < 64) *(float4*)&a2f[rr2[nt] * 68 + c0] = wv;
                    else         *(float4*)&wkf[rr2[nt] * 68 + (c0 - 64)] = wv;
                    if (tg == 0) {
                        if (h < 4) a2f[rr2[nt] * 68 + 64 + h] = wgt;
                        else       wkf[rr2[nt] * 68 + 64 + (h - 4)] = wgt;
                    }
                }
            }
        }
        __syncthreads();   // B_c: walk data ready

        // ---- walk (t<544) || stage next tile (544<=t<800) ----
        if (t < 544) {
            int ch = t % 136;
            int r0 = (t / 136) * 32;
            const int* dls = dls2[cur];
            float run = 0.0f;
            #pragma unroll 4
            for (int rr = 0; rr < 32; ++rr) {
                int r = r0 + rr;
                float v;
                if (ch < 64)       v = a2f[r * 68 + ch];
                else if (ch < 128) v = wkf[r * 68 + (ch - 64)];
                else if (ch < 132) v = a2f[r * 68 + 64 + (ch - 128)];
                else               v = wkf[r * 68 + 64 + (ch - 132)];
                run += v;
                if (rr == 31 || dls[r + 1] != dls[r]) {
                    int dn = dls[r];
                    if (ch < 128) atomicAdd(&num[(size_t)dn * CC + ch], run);
                    else          atomicAdd(&den[(size_t)dn * HH + (ch - 128)], run);
                    run = 0.0f;
                }
            }
        } else if (t < 800) {
            int nt2 = tile + gridDim.x;
            if (nt2 < ntiles) stage(nt2, nx, t - 544);
        }
        __syncthreads();   // B_d: close iteration
    }
}

// ---------------- output head ----------------
__global__ __launch_bounds__(64) void k_head(
    const float* __restrict__ h,
    const float* __restrict__ w1, const float* __restrict__ b1,
    const float* __restrict__ w2, const float* __restrict__ b2,
    float* __restrict__ out)
{
    const int n = blockIdx.x;
    const int j = threadIdx.x;
    float acc = 0.0f;
    for (int k = 0; k < CC; ++k)
        acc = fmaf(h[(size_t)n * CC + k], w1[k * 64 + j], acc);
    float m = sspf(acc + b1[j]);
    float o = m * w2[j];
    #pragma unroll
    for (int msk = 32; msk > 0; msk >>= 1) o += __shfl_xor(o, msk);
    if (j == 0) out[n] = o + b2[0];
}

extern "C" void kernel_launch(void* const* d_in, const int* in_sizes, int n_in,
                              void* d_out, int out_size, void* d_ws, size_t ws_size,
                              hipStream_t stream)
{
    const int*   z   = (const int*)d_in[0];
    const float* pos = (const float*)d_in[1];
    const int*   ei  = (const int*)d_in[2];
    const float* emb = (const float*)d_in[3];
    const float* w1  = (const float*)d_in[4];
    const float* b1  = (const float*)d_in[5];
    const float* w2  = (const float*)d_in[6];
    const float* b2  = (const float*)d_in[7];
    const float* wq  = (const float*)d_in[8];
    const float* bq  = (const float*)d_in[9];
    const float* wk  = (const float*)d_in[10];
    const float* bk  = (const float*)d_in[11];
    const float* wv  = (const float*)d_in[12];
    const float* bv  = (const float*)d_in[13];
    const float* we  = (const float*)d_in[14];
    const float* be  = (const float*)d_in[15];
    const float* wsk = (const float*)d_in[16];
    const float* bsk = (const float*)d_in[17];
    const float* wl  = (const float*)d_in[18];
    const float* bl  = (const float*)d_in[19];
    const float* wo1 = (const float*)d_in[20];
    const float* bo1 = (const float*)d_in[21];
    const float* wo2 = (const float*)d_in[22];
    const float* bo2 = (const float*)d_in[23];

    char* p = (char*)d_ws;
    auto alloc = [&](size_t bytes) -> void* {
        void* r = (void*)p; p += (bytes + 255) & ~(size_t)255; return r;
    };
    float* h    = (float*)alloc((size_t)NN * CC * 4);
    float* q    = (float*)alloc((size_t)NN * CC * 4);
    float* kk   = (float*)alloc((size_t)NN * CC * 4);
    float* vv   = (float*)alloc((size_t)NN * CC * 4);
    float* skip = (float*)alloc((size_t)NN * CC * 4);
    float* num  = (float*)alloc((size_t)NN * CC * 4);
    float* den  = (float*)alloc((size_t)NN * HH * 4);
    u16* w1tg  = (u16*)alloc((size_t)LL * 128 * 64 * 2);
    u16* w23tg = (u16*)alloc((size_t)LL * 128 * 128 * 2);
    float* b23g = (float*)alloc((size_t)LL * 128 * 4);
    u16* wn    = (u16*)alloc((size_t)LL * 5 * 128 * 128 * 2);
    int* count  = (int*)alloc((size_t)(NN + 1) * 4);
    int* rowptr = (int*)alloc((size_t)(NN + 1) * 4);
    int* cursor = (int*)alloc((size_t)NN * 4);
    int* srcp   = (int*)alloc((size_t)NE * 4);
    int* dstp   = (int*)alloc((size_t)NE * 4);

    k_zero<<<(NN + 255) / 256, 256, 0, stream>>>(count, NN);
    k_hist<<<(NE + 255) / 256, 256, 0, stream>>>(ei, count);
    k_scan<<<1, 1024, 0, stream>>>(count, rowptr, cursor);
    k_scatter<<<(NE + 255) / 256, 256, 0, stream>>>(ei, cursor, srcp, dstp);
    k_hinit<<<(NN * CC + 255) / 256, 256, 0, stream>>>(z, emb, h);
    k_prep1<<<(LL * 128 * 64 + 255) / 256, 256, 0, stream>>>(w1, w1tg);
    k_prep23<<<LL * 128, 128, 0, stream>>>(w2, we, w23tg);
    k_prepb<<<LL, 128, 0, stream>>>(b2, we, be, b23g);
    k_prepn<<<(LL * 5 * 128 * 128 + 255) / 256, 256, 0, stream>>>(wq, wk, wv, wsk, wl, wn);

    const int NT = (NN + 127) / 128;   // 157
    for (int l = 0; l < LL; ++l) {
        const u16* wnl = wn + (size_t)l * 5 * 16384;
        k_qkvs_mfma<<<NT * 4, 256, 0, stream>>>(h, wnl,
            bq + l * CC, bk + l * CC, bv + l * CC, bsk + l * CC,
            q, kk, vv, skip, num, den, NN);
        k_edge<<<256, 1024, 0, stream>>>(srcp, dstp, pos,
            w1tg + (size_t)l * 128 * 64, w23tg + (size_t)l * 128 * 128,
            b1 + l * FF, b23g + l * CC,
            q, kk, vv, num, den, NE / TE);
        k_upd_mfma<<<NT, 256, 0, stream>>>(num, den, skip,
            wnl + 4 * 16384, bl + l * CC, h, NN);
    }
    k_head<<<NN, 64, 0, stream>>>(h, wo1, bo1, wo2, bo2, (float*)d_out);
}